// Round 18
// baseline (257.534 us; speedup 1.0000x reference)
//
#include <hip/hip_runtime.h>
#include <math.h>

#define NATOMS 10000
#define NEDGES 320000
#define NBINS  (NATOMS * 4)   // bin = atom*4 + species; bin a*4+3 always empty
#define RC_F 5.0f
#define PI_F 3.14159265358979323846f
#define TABN 8192             // lerp table over d in [0, RC]; 1.6 MB -> L2-resident

// ---- workspace layout (in floats) ----
#define WS_SEMB   0         // 12 floats
#define WS_GTOT   12        // 1 int global allocation cursor
#define WS_CNT    16        // NBINS ints
#define WS_OFFS   40016     // NBINS ints (int4/atom: run starts t=0,1,2 + end)
#define WS_CURSOR 80016     // NBINS ints
#define WS_EIDX   120016    // NEDGES ints: edge id, (atom,species)-sorted
#define WS_TAB    440096    // (TABN+1)*48 floats: R(d)*fc(d) table (16B aligned)

// multinomial term tables (global component index 0..34)
__device__ __constant__ int   d_PWA[35] = {0, 0,0,1, 0,0,0,1,1,2, 0,0,0,0,1,1,1,2,2,3, 0,0,0,0,0,1,1,1,1,2,2,2,3,3,4};
__device__ __constant__ int   d_PWB[35] = {0, 0,1,0, 0,1,2,0,1,0, 0,1,2,3,0,1,2,0,1,0, 0,1,2,3,4,0,1,2,3,0,1,2,0,1,0};
__device__ __constant__ int   d_PWC[35] = {0, 1,0,0, 2,1,0,1,0,0, 3,2,1,0,2,1,0,1,0,0, 4,3,2,1,0,3,2,1,0,2,1,0,1,0,0};
__device__ __constant__ float d_NM[35]  = {1.f, 1.f,1.f,1.f, 1.f,2.f,1.f,2.f,2.f,1.f,
                                           1.f,3.f,3.f,1.f,3.f,6.f,3.f,3.f,3.f,1.f,
                                           1.f,4.f,6.f,4.f,1.f,4.f,12.f,12.f,4.f,6.f,12.f,6.f,4.f,4.f,1.f};
__device__ __constant__ int   d_LBLK[35]= {0, 1,1,1, 2,2,2,2,2,2, 3,3,3,3,3,3,3,3,3,3, 4,4,4,4,4,4,4,4,4,4,4,4,4,4,4};
__device__ __constant__ int   d_L6[6]   = {0,1,4,10,20,35};

__device__ __forceinline__ float siluf(float x) { return x / (1.0f + __expf(-x)); }

__device__ __forceinline__ float2 f2fma(float2 a, float2 b, float2 c) {
  return make_float2(fmaf(a.x, b.x, c.x), fmaf(a.y, b.y, c.y));
}

__device__ __forceinline__ float psel(float x, int p) {
  float x2 = x * x;
  float r = 1.0f;
  r = (p == 1) ? x : r;
  r = (p == 2) ? x2 : r;
  r = (p == 3) ? x2 * x : r;
  r = (p == 4) ? x2 * x2 : r;
  return r;
}

__device__ __forceinline__ float4 lerp4(float4 a, float4 b, float f) {
  return make_float4(fmaf(f, b.x - a.x, a.x), fmaf(f, b.y - a.y, a.y),
                     fmaf(f, b.z - a.z, a.z), fmaf(f, b.w - a.w, a.w));
}

// ---------------- k_init ----------------
__global__ void k_init(const float* __restrict__ Ws1, const float* __restrict__ bs1,
                       const float* __restrict__ Ws2, const float* __restrict__ bs2,
                       float* __restrict__ ws)
{
  int tid = blockIdx.x * blockDim.x + threadIdx.x;
  int* cnt = (int*)(ws + WS_CNT);
  if (tid < NBINS) cnt[tid] = 0;
  if (tid == 0) *(int*)(ws + WS_GTOT) = 0;
  if (tid < 12) {
    int t = tid >> 2, s = tid & 3;
    float acc = bs2[s];
    for (int j = 0; j < 16; j++) acc += tanhf(Ws1[t * 16 + j] + bs1[j]) * Ws2[j * 4 + s];
    ws[WS_SEMB + tid] = acc;
  }
}

// ---------------- k_tab: build R(d)*fc(d) lookup table ----------------
__global__ __launch_bounds__(256) void k_tab(
    const float* __restrict__ Wr1, const float* __restrict__ br1,
    const float* __restrict__ Wr2, const float* __restrict__ br2,
    float* __restrict__ ws)
{
  int i = blockIdx.x * 256 + threadIdx.x;
  if (i > TABN) return;
  float d = (float)i * (RC_F / (float)TABN);
  float theta = (PI_F / RC_F) * d;
  float s1 = __sinf(theta), c1 = __cosf(theta);
  float fc = (d < RC_F) ? 0.5f * (c1 + 1.0f) : 0.0f;
  float bes[8];
  float sq = sqrtf(2.0f / RC_F);
  if (i == 0) {
    #pragma unroll
    for (int k = 0; k < 8; k++) bes[k] = sq * (float)(k + 1) * (PI_F / RC_F);  // lim sin(kθ)/d
  } else {
    float invd = 1.0f / d;
    float twoc = 2.0f * c1;
    float sp = 0.0f, sc = s1;
    #pragma unroll
    for (int k = 0; k < 8; k++) {
      bes[k] = sq * invd * sc;
      float sn = twoc * sc - sp;
      sp = sc; sc = sn;
    }
  }
  float h1[64];
  #pragma unroll
  for (int j = 0; j < 64; j++) {
    float acc = br1[j];
    #pragma unroll
    for (int k = 0; k < 8; k++) acc += bes[k] * Wr1[k * 64 + j];
    h1[j] = siluf(acc);
  }
  float* row = ws + WS_TAB + (size_t)i * 48;
  for (int j = 0; j < 48; j++) {
    float acc = br2[j];
    #pragma unroll
    for (int k = 0; k < 64; k++) acc += h1[k] * Wr2[k * 48 + j];
    row[j] = siluf(acc) * fc;
  }
}

// ---------------- k_hist: (atom,species)-bin counts ----------------
__global__ void k_hist(const int* __restrict__ first_atom, const int* __restrict__ second_atom,
                       const int* __restrict__ species, float* __restrict__ ws)
{
  int e = blockIdx.x * blockDim.x + threadIdx.x;
  if (e < NEDGES) {
    int* cnt = (int*)(ws + WS_CNT);
    int bin = first_atom[e] * 4 + species[second_atom[e]];
    atomicAdd(&cnt[bin], 1);
  }
}

// ---------------- k_alloc: decentralized run allocation, int4 per atom ----------------
__global__ __launch_bounds__(256) void k_alloc(float* __restrict__ ws)
{
  const int4* cnt4 = (const int4*)(ws + WS_CNT);
  int4* offs4   = (int4*)(ws + WS_OFFS);
  int4* cursor4 = (int4*)(ws + WS_CURSOR);
  int* gtot = (int*)(ws + WS_GTOT);
  __shared__ int wsum[4];
  __shared__ int sbase;
  int tid = threadIdx.x;
  int lane = tid & 63, wv = tid >> 6;
  int a = blockIdx.x * 256 + tid;
  bool live = (a < NATOMS);
  int4 c = live ? cnt4[a] : make_int4(0, 0, 0, 0);
  int s = c.x + c.y + c.z + c.w;
  int inc = s;
  #pragma unroll
  for (int d = 1; d < 64; d <<= 1) {
    int v = __shfl_up(inc, d, 64);
    if (lane >= d) inc += v;
  }
  if (lane == 63) wsum[wv] = inc;
  __syncthreads();
  if (tid == 0) sbase = atomicAdd(gtot, wsum[0] + wsum[1] + wsum[2] + wsum[3]);
  __syncthreads();
  int woff = sbase;
  for (int w = 0; w < wv; w++) woff += wsum[w];
  int o0 = woff + inc - s;
  if (live) {
    int4 o;
    o.x = o0;
    o.y = o.x + c.x;
    o.z = o.y + c.y;
    o.w = o.z + c.z;
    offs4[a] = o;
    cursor4[a] = o;
  }
}

// ---------------- k_scatter: build (atom,species)-sorted edge-id lists ----------------
__global__ void k_scatter(const int* __restrict__ first_atom, const int* __restrict__ second_atom,
                          const int* __restrict__ species, float* __restrict__ ws)
{
  int e = blockIdx.x * blockDim.x + threadIdx.x;
  if (e < NEDGES) {
    int* cursor = (int*)(ws + WS_CURSOR);
    int* eidx   = (int*)(ws + WS_EIDX);
    int t = species[second_atom[e]];
    int pos = atomicAdd(&cursor[first_atom[e] * 4 + t], 1);
    eidx[pos] = e;
  }
}

// ---------------- k_atom: FUSED — table-lerp per edge, no staging arrays ----------------
// One wave per atom. Per chunk of <=64 edges: coalesced eidx load, per-lane rij
// gather + (i,f,rhat) computation; then per edge (wave-uniform): shfl-broadcast
// i/f/rhat, lanes load their own slice of the two table rows directly from L2
// (depth-2 register prefetch), lerp, 8-FMA accumulate. SA/SB round-trip is gone.
__global__ __launch_bounds__(128) void k_atom(
    const float* __restrict__ rij,
    const float* __restrict__ ws,
    const float* __restrict__ Wa1, const float* __restrict__ ba1,
    const float* __restrict__ Wa2, const float* __restrict__ ba2,
    const float* __restrict__ Wa3, const float* __restrict__ ba3,
    float* __restrict__ out)
{
  __shared__ __align__(16) float sScr[2][1120];   // per-wave: G 864 + feat 192 + h 64
  int tid = threadIdx.x;
  int lane = tid & 63, wv = tid >> 6;
  int a = blockIdx.x * 2 + wv;          // NATOMS = 5000*2 exact
  float* sG    = &sScr[wv][0];
  float* sFeat = &sScr[wv][864];
  float* sH    = &sScr[wv][1056];

  const int* eidx = (const int*)(ws + WS_EIDX);
  const float4* tab4 = (const float4*)(ws + WS_TAB);   // 12 float4 per row
  int4 o = ((const int4*)(ws + WS_OFFS))[a];

  const int c = lane;
  bool isc = (c < 35);
  int pa = 0, pb = 0, pcw = 0, lb = 0;
  if (isc) { pa = d_PWA[c]; pb = d_PWB[c]; pcw = d_PWC[c]; lb = d_LBLK[c]; }
  int rdir = lane - 35;
  bool isd = (rdir >= 0) && (rdir < 8);
  // per-lane float4 offset within a row: isc -> 2+2*lb (R[8+8lb..]), isd -> rdir>>2
  int off4 = isc ? (2 + 2 * lb) : (isd ? (rdir >> 2) : 0);
  int dcomp = rdir & 3;

  float2 g2[3][4];
  #pragma unroll
  for (int t2 = 0; t2 < 3; t2++)
    #pragma unroll
    for (int r = 0; r < 4; r++) g2[t2][r] = make_float2(0.f, 0.f);
  float g0[3] = {0.0f, 0.0f, 0.0f};

#define LOADT(J, A0, A1, B0, B1) {                                            \
    int ij_ = __shfl(iv, (J), 64);                                            \
    const float4* rp = tab4 + ij_ * 12 + off4;                                \
    A0 = rp[0]; A1 = rp[1]; B0 = rp[12]; B1 = rp[13];                         \
  }

#define CORE(T, A0, A1, B0, B1) {                                             \
    float fj = __shfl(fv, j, 64);                                             \
    float xj = __shfl(rhx, j, 64);                                            \
    float yj = __shfl(rhy, j, 64);                                            \
    float zj = __shfl(rhz, j, 64);                                            \
    if (isc) {                                                                \
      float comp = psel(xj, pa) * psel(yj, pb) * psel(zj, pcw);               \
      float4 Ra = lerp4(A0, B0, fj);                                          \
      float4 Rb = lerp4(A1, B1, fj);                                          \
      float2 c2 = make_float2(comp, comp);                                    \
      g2[T][0] = f2fma(c2, make_float2(Ra.x, Ra.y), g2[T][0]);                \
      g2[T][1] = f2fma(c2, make_float2(Ra.z, Ra.w), g2[T][1]);                \
      g2[T][2] = f2fma(c2, make_float2(Rb.x, Rb.y), g2[T][2]);                \
      g2[T][3] = f2fma(c2, make_float2(Rb.z, Rb.w), g2[T][3]);                \
    } else if (isd) {                                                         \
      float w0 = (dcomp == 0) ? A0.x : (dcomp == 1) ? A0.y : (dcomp == 2) ? A0.z : A0.w; \
      float w1 = (dcomp == 0) ? B0.x : (dcomp == 1) ? B0.y : (dcomp == 2) ? B0.z : B0.w; \
      g0[T] += fmaf(fj, w1 - w0, w0);                                         \
    }                                                                         \
  }

#define RUN(T, LO, HI)                                                        \
  for (int cb = (LO); cb < (HI); cb += 64) {                                  \
    int m = (HI) - cb; if (m > 64) m = 64;                                    \
    int pp = cb + lane;                                                       \
    int e = eidx[pp < (HI) ? pp : ((HI) - 1)];                                \
    float x = rij[e * 3 + 0], y = rij[e * 3 + 1], z = rij[e * 3 + 2];         \
    float d = sqrtf(x * x + y * y + z * z + 1e-12f);                          \
    float invd = 1.0f / d;                                                    \
    float rhx = x * invd, rhy = y * invd, rhz = z * invd;                     \
    float u = d * ((float)TABN / RC_F);                                       \
    int iv = (int)u; if (iv > TABN - 1) iv = TABN - 1;                        \
    float fv = u - (float)iv;                                                 \
    float4 a0, a1, b0, b1, c0, c1, d0, d1;                                    \
    LOADT(0, a0, a1, b0, b1)                                                  \
    if (m > 1) { LOADT(1, c0, c1, d0, d1) }                                   \
    for (int j = 0; j < m; j++) {                                             \
      if (j & 1) {                                                            \
        CORE(T, c0, c1, d0, d1)                                               \
        if (j + 2 < m) LOADT(j + 2, c0, c1, d0, d1)                           \
      } else {                                                                \
        CORE(T, a0, a1, b0, b1)                                               \
        if (j + 2 < m) LOADT(j + 2, a0, a1, b0, b1)                           \
      }                                                                       \
    }                                                                         \
  }

  RUN(0, o.x, o.y)
  RUN(1, o.y, o.z)
  RUN(2, o.z, o.w)
#undef RUN
#undef CORE
#undef LOADT

  // transpose G into LDS (same-wave, no barrier)
  if (isc) {
    #pragma unroll
    for (int t2 = 0; t2 < 3; t2++)
      #pragma unroll
      for (int r = 0; r < 8; r++) {
        float gval = (r & 1) ? g2[t2][r >> 1].y : g2[t2][r >> 1].x;
        sG[(t2 * 8 + r) * 36 + c] = gval;
      }
  } else if (isd) {
    #pragma unroll
    for (int t2 = 0; t2 < 3; t2++) sG[(t2 * 8 + rdir) * 36 + 35] = g0[t2];
  }

  // contraction: lane owns feats {lane, lane+64, lane+128}; f=(blk*8+rr)*4+s
  int s = lane & 3;
  float se0 = ws[WS_SEMB + s], se1 = ws[WS_SEMB + 4 + s], se2 = ws[WS_SEMB + 8 + s];
  float fout[3];
  #pragma unroll
  for (int u = 0; u < 3; u++) {
    int f = lane + 64 * u;
    int blk = f >> 5, rr = (f >> 2) & 7;
    float acc;
    if (blk == 0) {
      acc = se0 * sG[(0 + rr) * 36 + 35] + se1 * sG[(8 + rr) * 36 + 35] + se2 * sG[(16 + rr) * 36 + 35];
    } else {
      int c0i = d_L6[blk - 1], c1i = d_L6[blk];
      acc = 0.0f;
      for (int cc = c0i; cc < c1i; cc++) {
        float A = se0 * sG[(0 + rr) * 36 + cc] + se1 * sG[(8 + rr) * 36 + cc] + se2 * sG[(16 + rr) * 36 + cc];
        acc += d_NM[cc] * A * A;
      }
    }
    fout[u] = acc;
  }
  #pragma unroll
  for (int u = 0; u < 3; u++) sFeat[lane + 64 * u] = fout[u];

  // MLP layer 1: 192 -> 64
  {
    float a0 = 0.f, a1 = 0.f, a2 = 0.f, a3 = 0.f;
    for (int k4 = 0; k4 < 48; k4++) {
      float4 f4 = *(const float4*)(sFeat + k4 * 4);
      const float* w = Wa1 + (k4 * 4) * 64 + lane;
      a0 += f4.x * w[0];
      a1 += f4.y * w[64];
      a2 += f4.z * w[128];
      a3 += f4.w * w[192];
    }
    sH[lane] = siluf(a0 + a1 + a2 + a3 + ba1[lane]);
  }

  // MLP layer 2: 64 -> 64, layer 3 + wave reduction
  {
    float a0 = 0.f, a1 = 0.f, a2 = 0.f, a3 = 0.f;
    for (int k4 = 0; k4 < 16; k4++) {
      float4 h4 = *(const float4*)(sH + k4 * 4);
      const float* w = Wa2 + (k4 * 4) * 64 + lane;
      a0 += h4.x * w[0];
      a1 += h4.y * w[64];
      a2 += h4.z * w[128];
      a3 += h4.w * w[192];
    }
    float h2 = siluf(a0 + a1 + a2 + a3 + ba2[lane]);
    float pr = h2 * Wa3[lane];
    #pragma unroll
    for (int off = 32; off > 0; off >>= 1) pr += __shfl_down(pr, off, 64);
    if (lane == 0) out[a] = pr + ba3[0];
  }
}

extern "C" void kernel_launch(void* const* d_in, const int* in_sizes, int n_in,
                              void* d_out, int out_size, void* d_ws, size_t ws_size,
                              hipStream_t stream)
{
  const float* rij         = (const float*)d_in[0];
  const int*   species     = (const int*)  d_in[1];
  const int*   first_atom  = (const int*)  d_in[2];
  const int*   second_atom = (const int*)  d_in[3];
  const float* Wr1 = (const float*)d_in[4];
  const float* br1 = (const float*)d_in[5];
  const float* Wr2 = (const float*)d_in[6];
  const float* br2 = (const float*)d_in[7];
  const float* Ws1 = (const float*)d_in[8];
  const float* bs1 = (const float*)d_in[9];
  const float* Ws2 = (const float*)d_in[10];
  const float* bs2 = (const float*)d_in[11];
  const float* Wa1 = (const float*)d_in[12];
  const float* ba1 = (const float*)d_in[13];
  const float* Wa2 = (const float*)d_in[14];
  const float* ba2 = (const float*)d_in[15];
  const float* Wa3 = (const float*)d_in[16];
  const float* ba3 = (const float*)d_in[17];
  float* ws  = (float*)d_ws;
  float* out = (float*)d_out;

  k_init<<<(NBINS + 255) / 256, 256, 0, stream>>>(Ws1, bs1, Ws2, bs2, ws);
  k_tab<<<(TABN + 256) / 256, 256, 0, stream>>>(Wr1, br1, Wr2, br2, ws);
  k_hist<<<(NEDGES + 255) / 256, 256, 0, stream>>>(first_atom, second_atom, species, ws);
  k_alloc<<<(NATOMS + 255) / 256, 256, 0, stream>>>(ws);
  k_scatter<<<(NEDGES + 255) / 256, 256, 0, stream>>>(first_atom, second_atom, species, ws);
  k_atom<<<NATOMS / 2, 128, 0, stream>>>(rij, ws, Wa1, ba1, Wa2, ba2, Wa3, ba3, out);
}

// Round 19
// 213.588 us; speedup vs baseline: 1.2058x; 1.2058x over previous
//
#include <hip/hip_runtime.h>
#include <math.h>

#define NATOMS 10000
#define NEDGES 320000
#define NBINS  (NATOMS * 4)   // bin = atom*4 + species; bin a*4+3 always empty
#define RC_F 5.0f
#define PI_F 3.14159265358979323846f

// ---- workspace layout (in floats) ----
#define WS_SEMB   0         // 12 floats
#define WS_GTOT   12        // 1 int global allocation cursor
#define WS_CNT    16        // NBINS ints
#define WS_OFFS   40016     // NBINS ints (int4/atom: run starts t=0,1,2 + end)
#define WS_CURSOR 80016     // NBINS ints
#define WS_EIDX   120016    // NEDGES ints: edge id, (atom,species)-sorted
#define WS_SA     440096    // NEDGES*32 floats: R[0..23] (+pad), 128B recs
#define WS_SB     10680096  // NEDGES*32 floats: R[24..47], rhat (+pad)

// multinomial term tables (global component index 0..34)
__device__ __constant__ int   d_PWA[35] = {0, 0,0,1, 0,0,0,1,1,2, 0,0,0,0,1,1,1,2,2,3, 0,0,0,0,0,1,1,1,1,2,2,2,3,3,4};
__device__ __constant__ int   d_PWB[35] = {0, 0,1,0, 0,1,2,0,1,0, 0,1,2,3,0,1,2,0,1,0, 0,1,2,3,4,0,1,2,3,0,1,2,0,1,0};
__device__ __constant__ int   d_PWC[35] = {0, 1,0,0, 2,1,0,1,0,0, 3,2,1,0,2,1,0,1,0,0, 4,3,2,1,0,3,2,1,0,2,1,0,1,0,0};
__device__ __constant__ float d_NM[35]  = {1.f, 1.f,1.f,1.f, 1.f,2.f,1.f,2.f,2.f,1.f,
                                           1.f,3.f,3.f,1.f,3.f,6.f,3.f,3.f,3.f,1.f,
                                           1.f,4.f,6.f,4.f,1.f,4.f,12.f,12.f,4.f,6.f,12.f,6.f,4.f,4.f,1.f};
__device__ __constant__ int   d_LBLK[35]= {0, 1,1,1, 2,2,2,2,2,2, 3,3,3,3,3,3,3,3,3,3, 4,4,4,4,4,4,4,4,4,4,4,4,4,4,4};
__device__ __constant__ int   d_L6[6]   = {0,1,4,10,20,35};

__device__ __forceinline__ float siluf(float x) { return x / (1.0f + __expf(-x)); }

__device__ __forceinline__ float2 f2fma(float2 a, float2 b, float2 c) {
  return make_float2(fmaf(a.x, b.x, c.x), fmaf(a.y, b.y, c.y));
}

__device__ __forceinline__ float psel(float x, int p) {
  float x2 = x * x;
  float r = 1.0f;
  r = (p == 1) ? x : r;
  r = (p == 2) ? x2 : r;
  r = (p == 3) ? x2 * x : r;
  r = (p == 4) ? x2 * x2 : r;
  return r;
}

// ---------------- k_init ----------------
__global__ void k_init(const float* __restrict__ Ws1, const float* __restrict__ bs1,
                       const float* __restrict__ Ws2, const float* __restrict__ bs2,
                       float* __restrict__ ws)
{
  int tid = blockIdx.x * blockDim.x + threadIdx.x;
  int* cnt = (int*)(ws + WS_CNT);
  if (tid < NBINS) cnt[tid] = 0;
  if (tid == 0) *(int*)(ws + WS_GTOT) = 0;
  if (tid < 12) {
    int t = tid >> 2, s = tid & 3;
    float acc = bs2[s];
    for (int j = 0; j < 16; j++) acc += tanhf(Ws1[t * 16 + j] + bs1[j]) * Ws2[j * 4 + s];
    ws[WS_SEMB + tid] = acc;
  }
}

// ---------------- k_hist: (atom,species)-bin counts ----------------
__global__ void k_hist(const int* __restrict__ first_atom, const int* __restrict__ second_atom,
                       const int* __restrict__ species, float* __restrict__ ws)
{
  int e = blockIdx.x * blockDim.x + threadIdx.x;
  if (e < NEDGES) {
    int* cnt = (int*)(ws + WS_CNT);
    int bin = first_atom[e] * 4 + species[second_atom[e]];
    atomicAdd(&cnt[bin], 1);
  }
}

// ---------------- k_alloc: decentralized run allocation, int4 per atom ----------------
__global__ __launch_bounds__(256) void k_alloc(float* __restrict__ ws)
{
  const int4* cnt4 = (const int4*)(ws + WS_CNT);
  int4* offs4   = (int4*)(ws + WS_OFFS);
  int4* cursor4 = (int4*)(ws + WS_CURSOR);
  int* gtot = (int*)(ws + WS_GTOT);
  __shared__ int wsum[4];
  __shared__ int sbase;
  int tid = threadIdx.x;
  int lane = tid & 63, wv = tid >> 6;
  int a = blockIdx.x * 256 + tid;
  bool live = (a < NATOMS);
  int4 c = live ? cnt4[a] : make_int4(0, 0, 0, 0);
  int s = c.x + c.y + c.z + c.w;
  int inc = s;
  #pragma unroll
  for (int d = 1; d < 64; d <<= 1) {
    int v = __shfl_up(inc, d, 64);
    if (lane >= d) inc += v;
  }
  if (lane == 63) wsum[wv] = inc;
  __syncthreads();
  if (tid == 0) sbase = atomicAdd(gtot, wsum[0] + wsum[1] + wsum[2] + wsum[3]);
  __syncthreads();
  int woff = sbase;
  for (int w = 0; w < wv; w++) woff += wsum[w];
  int o0 = woff + inc - s;
  if (live) {
    int4 o;
    o.x = o0;
    o.y = o.x + c.x;
    o.z = o.y + c.y;
    o.w = o.z + c.z;
    offs4[a] = o;
    cursor4[a] = o;
  }
}

// ---------------- k_edge: packed-FMA MLP -> half-record LDS rows -> 2 coalesced bursts ----------------
__global__ __launch_bounds__(256) void k_edge(
    const float* __restrict__ rij, const int* __restrict__ species,
    const int* __restrict__ first_atom, const int* __restrict__ second_atom,
    const float* __restrict__ Wr1, const float* __restrict__ br1,
    const float* __restrict__ Wr2, const float* __restrict__ br2,
    float* __restrict__ ws)
{
  __shared__ __align__(16) float sRec[4][64 * 28];
  int tid = threadIdx.x, lane = tid & 63, wv = tid >> 6;
  int e = blockIdx.x * 256 + tid;
  int* cursor = (int*)(ws + WS_CURSOR);
  int* eidx   = (int*)(ws + WS_EIDX);
  float* myrow = &sRec[wv][lane * 28];

  int a = first_atom[e];
  int t = species[second_atom[e]];
  int pos = atomicAdd(&cursor[a * 4 + t], 1);
  eidx[pos] = e;

  float x = rij[e * 3 + 0], y = rij[e * 3 + 1], z = rij[e * 3 + 2];
  float d = sqrtf(x * x + y * y + z * z + 1e-12f);
  float invd = 1.0f / d;

  float theta = (PI_F / RC_F) * d;
  float s1 = __sinf(theta), c1 = __cosf(theta);
  float fc = (d < RC_F) ? 0.5f * (c1 + 1.0f) : 0.0f;
  float bes[8];
  {
    float sq = sqrtf(2.0f / RC_F) * invd;
    float twoc = 2.0f * c1;
    float sp = 0.0f, sc = s1;
    #pragma unroll
    for (int k = 0; k < 8; k++) {
      bes[k] = sq * sc;
      float sn = twoc * sc - sp;
      sp = sc; sc = sn;
    }
  }

  float h1[64];
  #pragma unroll
  for (int j4 = 0; j4 < 16; j4++) {
    float2 a01 = *(const float2*)&br1[j4 * 4];
    float2 a23 = *(const float2*)&br1[j4 * 4 + 2];
    #pragma unroll
    for (int k = 0; k < 8; k++) {
      float2 b2 = make_float2(bes[k], bes[k]);
      a01 = f2fma(b2, *(const float2*)&Wr1[k * 64 + j4 * 4],     a01);
      a23 = f2fma(b2, *(const float2*)&Wr1[k * 64 + j4 * 4 + 2], a23);
    }
    h1[j4 * 4 + 0] = siluf(a01.x);
    h1[j4 * 4 + 1] = siluf(a01.y);
    h1[j4 * 4 + 2] = siluf(a23.x);
    h1[j4 * 4 + 3] = siluf(a23.y);
  }

  int ebase = blockIdx.x * 256 + wv * 64;
  const float* buf = &sRec[wv][0];
  int f4 = lane & 7;

  for (int j4 = 0; j4 < 6; j4++) {
    float2 a01 = *(const float2*)&br2[j4 * 4];
    float2 a23 = *(const float2*)&br2[j4 * 4 + 2];
    #pragma unroll
    for (int k = 0; k < 64; k++) {
      float2 h2 = make_float2(h1[k], h1[k]);
      a01 = f2fma(h2, *(const float2*)&Wr2[k * 48 + j4 * 4],     a01);
      a23 = f2fma(h2, *(const float2*)&Wr2[k * 48 + j4 * 4 + 2], a23);
    }
    *(float4*)(myrow + j4 * 4) = make_float4(siluf(a01.x) * fc, siluf(a01.y) * fc,
                                             siluf(a23.x) * fc, siluf(a23.y) * fc);
  }
  {
    float* gbase = ws + WS_SA + (size_t)ebase * 32;
    if (f4 < 6) {
      #pragma unroll
      for (int q = 0; q < 8; q++) {
        int g4 = q * 64 + lane;
        float4 v = *(const float4*)(buf + (g4 >> 3) * 28 + f4 * 4);
        *(float4*)(gbase + (size_t)g4 * 4) = v;
      }
    }
  }

  for (int j4 = 6; j4 < 12; j4++) {
    float2 a01 = *(const float2*)&br2[j4 * 4];
    float2 a23 = *(const float2*)&br2[j4 * 4 + 2];
    #pragma unroll
    for (int k = 0; k < 64; k++) {
      float2 h2 = make_float2(h1[k], h1[k]);
      a01 = f2fma(h2, *(const float2*)&Wr2[k * 48 + j4 * 4],     a01);
      a23 = f2fma(h2, *(const float2*)&Wr2[k * 48 + j4 * 4 + 2], a23);
    }
    *(float4*)(myrow + (j4 - 6) * 4) = make_float4(siluf(a01.x) * fc, siluf(a01.y) * fc,
                                                   siluf(a23.x) * fc, siluf(a23.y) * fc);
  }
  *(float4*)(myrow + 24) = make_float4(x * invd, y * invd, z * invd, 0.0f);
  {
    float* gbase = ws + WS_SB + (size_t)ebase * 32;
    if (f4 < 7) {
      #pragma unroll
      for (int q = 0; q < 8; q++) {
        int g4 = q * 64 + lane;
        float4 v = *(const float4*)(buf + (g4 >> 3) * 28 + f4 * 4);
        *(float4*)(gbase + (size_t)g4 * 4) = v;
      }
    }
  }
}

// ---------------- k_atom: one wave per atom, species-homogeneous runs, 8-FMA CORE ----------------
__global__ __launch_bounds__(128) void k_atom(
    const float* __restrict__ ws,
    const float* __restrict__ Wa1, const float* __restrict__ ba1,
    const float* __restrict__ Wa2, const float* __restrict__ ba2,
    const float* __restrict__ Wa3, const float* __restrict__ ba3,
    float* __restrict__ out)
{
  __shared__ __align__(16) float sScr[2][1920];
  int tid = threadIdx.x;
  int lane = tid & 63, wv = tid >> 6;
  int a = blockIdx.x * 2 + wv;          // NATOMS = 5000*2 exact
  float* sStage = &sScr[wv][0];
  float* sG     = &sScr[wv][768];
  float* sFeat  = &sScr[wv][1632];
  float* sH     = &sScr[wv][1824];

  const int* eidx = (const int*)(ws + WS_EIDX);
  int4 o = ((const int4*)(ws + WS_OFFS))[a];

  const int c = lane;
  bool isc = (c < 35);
  int pa = 0, pb = 0, pcw = 0, lb = 0;
  if (isc) { pa = d_PWA[c]; pb = d_PWB[c]; pcw = d_PWC[c]; lb = d_LBLK[c]; }
  int rdir = lane - 35;
  bool isd = (rdir >= 0) && (rdir < 8);
  int rl = lane >> 4, fl = lane & 15;
  const float* gsrc = ws + (fl < 6 ? WS_SA : WS_SB);
  int foff = (fl < 6) ? fl : ((fl < 13) ? fl - 6 : 6);

  float2 g2[3][4];
  #pragma unroll
  for (int t2 = 0; t2 < 3; t2++)
    #pragma unroll
    for (int r = 0; r < 4; r++) g2[t2][r] = make_float2(0.f, 0.f);
  float g0[3] = {0.0f, 0.0f, 0.0f};

#define CORE(T) {                                                             \
    const float* rb = buf + j * 64;                                           \
    if (isc) {                                                                \
      float comp = psel(rb[48], pa) * psel(rb[49], pb) * psel(rb[50], pcw);   \
      float2 c2 = make_float2(comp, comp);                                    \
      const float2* r2 = (const float2*)(rb + 8 + 8 * lb);                    \
      g2[T][0] = f2fma(c2, r2[0], g2[T][0]);                                  \
      g2[T][1] = f2fma(c2, r2[1], g2[T][1]);                                  \
      g2[T][2] = f2fma(c2, r2[2], g2[T][2]);                                  \
      g2[T][3] = f2fma(c2, r2[3], g2[T][3]);                                  \
    } else if (isd) {                                                         \
      g0[T] += rb[rdir];                                                      \
    }                                                                         \
  }

#define LOADR(Q, DST) {                                                       \
    int sl_ = (Q) * 4 + rl; if (sl_ >= m) sl_ = m - 1;                        \
    int pk_ = __shfl(packed, sl_, 64);                                        \
    DST = *(const float4*)(gsrc + (size_t)pk_ * 32 + foff * 4);               \
  }

#define RUN(T, LO, HI)                                                        \
  for (int cb = (LO); cb < (HI); cb += 64) {                                  \
    int m = (HI) - cb; if (m > 64) m = 64;                                    \
    int pp = cb + lane;                                                       \
    int packed = eidx[pp < (HI) ? pp : (LO)];                                 \
    int R = (m + 3) >> 2;                                                     \
    float4 v0, v1;                                                            \
    LOADR(0, v0)                                                              \
    if (R > 1) { LOADR(1, v1) } else v1 = v0;                                 \
    int bsel = 0;                                                             \
    for (int r = 0; r < R; r++) {                                             \
      float* buf = sStage + (bsel << 8);                                      \
      bsel = (bsel == 2) ? 0 : bsel + 1;                                      \
      *(float4*)(buf + rl * 64 + fl * 4) = v0;                                \
      v0 = v1;                                                                \
      if (r + 2 < R) LOADR(r + 2, v1)                                         \
      int g = r * 4, gm = m - g; if (gm > 4) gm = 4;                          \
      for (int j = 0; j < gm; j++) CORE(T)                                    \
    }                                                                         \
  }

  RUN(0, o.x, o.y)
  RUN(1, o.y, o.z)
  RUN(2, o.z, o.w)
#undef RUN
#undef CORE
#undef LOADR

  if (isc) {
    #pragma unroll
    for (int t2 = 0; t2 < 3; t2++)
      #pragma unroll
      for (int r = 0; r < 8; r++) {
        float gval = (r & 1) ? g2[t2][r >> 1].y : g2[t2][r >> 1].x;
        sG[(t2 * 8 + r) * 36 + c] = gval;
      }
  } else if (isd) {
    #pragma unroll
    for (int t2 = 0; t2 < 3; t2++) sG[(t2 * 8 + rdir) * 36 + 35] = g0[t2];
  }

  int s = lane & 3;
  float se0 = ws[WS_SEMB + s], se1 = ws[WS_SEMB + 4 + s], se2 = ws[WS_SEMB + 8 + s];
  float fout[3];
  #pragma unroll
  for (int u = 0; u < 3; u++) {
    int f = lane + 64 * u;
    int blk = f >> 5, rr = (f >> 2) & 7;
    float acc;
    if (blk == 0) {
      acc = se0 * sG[(0 + rr) * 36 + 35] + se1 * sG[(8 + rr) * 36 + 35] + se2 * sG[(16 + rr) * 36 + 35];
    } else {
      int c0 = d_L6[blk - 1], c1 = d_L6[blk];
      acc = 0.0f;
      for (int cc = c0; cc < c1; cc++) {
        float A = se0 * sG[(0 + rr) * 36 + cc] + se1 * sG[(8 + rr) * 36 + cc] + se2 * sG[(16 + rr) * 36 + cc];
        acc += d_NM[cc] * A * A;
      }
    }
    fout[u] = acc;
  }
  #pragma unroll
  for (int u = 0; u < 3; u++) sFeat[lane + 64 * u] = fout[u];

  {
    float a0 = 0.f, a1 = 0.f, a2 = 0.f, a3 = 0.f;
    for (int k4 = 0; k4 < 48; k4++) {
      float4 f4 = *(const float4*)(sFeat + k4 * 4);
      const float* w = Wa1 + (k4 * 4) * 64 + lane;
      a0 += f4.x * w[0];
      a1 += f4.y * w[64];
      a2 += f4.z * w[128];
      a3 += f4.w * w[192];
    }
    sH[lane] = siluf(a0 + a1 + a2 + a3 + ba1[lane]);
  }

  {
    float a0 = 0.f, a1 = 0.f, a2 = 0.f, a3 = 0.f;
    for (int k4 = 0; k4 < 16; k4++) {
      float4 h4 = *(const float4*)(sH + k4 * 4);
      const float* w = Wa2 + (k4 * 4) * 64 + lane;
      a0 += h4.x * w[0];
      a1 += h4.y * w[64];
      a2 += h4.z * w[128];
      a3 += h4.w * w[192];
    }
    float h2 = siluf(a0 + a1 + a2 + a3 + ba2[lane]);
    float pr = h2 * Wa3[lane];
    #pragma unroll
    for (int off = 32; off > 0; off >>= 1) pr += __shfl_down(pr, off, 64);
    if (lane == 0) out[a] = pr + ba3[0];
  }
}

extern "C" void kernel_launch(void* const* d_in, const int* in_sizes, int n_in,
                              void* d_out, int out_size, void* d_ws, size_t ws_size,
                              hipStream_t stream)
{
  const float* rij         = (const float*)d_in[0];
  const int*   species     = (const int*)  d_in[1];
  const int*   first_atom  = (const int*)  d_in[2];
  const int*   second_atom = (const int*)  d_in[3];
  const float* Wr1 = (const float*)d_in[4];
  const float* br1 = (const float*)d_in[5];
  const float* Wr2 = (const float*)d_in[6];
  const float* br2 = (const float*)d_in[7];
  const float* Ws1 = (const float*)d_in[8];
  const float* bs1 = (const float*)d_in[9];
  const float* Ws2 = (const float*)d_in[10];
  const float* bs2 = (const float*)d_in[11];
  const float* Wa1 = (const float*)d_in[12];
  const float* ba1 = (const float*)d_in[13];
  const float* Wa2 = (const float*)d_in[14];
  const float* ba2 = (const float*)d_in[15];
  const float* Wa3 = (const float*)d_in[16];
  const float* ba3 = (const float*)d_in[17];
  float* ws  = (float*)d_ws;
  float* out = (float*)d_out;

  k_init<<<(NBINS + 255) / 256, 256, 0, stream>>>(Ws1, bs1, Ws2, bs2, ws);
  k_hist<<<(NEDGES + 255) / 256, 256, 0, stream>>>(first_atom, second_atom, species, ws);
  k_alloc<<<(NATOMS + 255) / 256, 256, 0, stream>>>(ws);
  k_edge<<<NEDGES / 256, 256, 0, stream>>>(rij, species, first_atom, second_atom,
                                           Wr1, br1, Wr2, br2, ws);
  k_atom<<<NATOMS / 2, 128, 0, stream>>>(ws, Wa1, ba1, Wa2, ba2, Wa3, ba3, out);
}